// Round 2
// 661.049 us; speedup vs baseline: 1.0678x; 1.0678x over previous
//
#include <hip/hip_runtime.h>

#define IMG_H 512
#define IMG_W 512
#define WOUT  128          // output cols per block
#define WV    144          // WOUT + 16 halo cols (valid data cols per row)
#define SP    296          // sin_ slot pitch (floats); 296*4=1184B, 2-slot stride = 16-bank shift
#define SB    148          // b2 plane offset within a slot (floats), 592B (16B aligned)
#define NRING 24           // circular input row slots (16 halo + 8 step rows)
#define RS    8            // rows per step
#define NSTEP 8            // steps per block (64-row strip)
#define SVP   152          // sv_ row pitch (floats); 608B, 2-row stride = 16-bank shift
#define PS    (RS * SVP)   // sv_ plane stride (floats) = 1216
#define C1F   1.0e-4f
#define C2F   9.0e-4f

// ---------------------------------------------------------------------------
// prep: extract exact separable 1D weights from the 2D filters.
// g2d[i][j] == v[i]*v[j] with v[j] = g[h][j]/sqrt(g[h][h])  (outer product).
// ws layout (floats): [0..4]=w5, [8..18]=w11, [32..48]=w17
// ---------------------------------------------------------------------------
__global__ void prep_weights_kernel(const float* __restrict__ g0,
                                    const float* __restrict__ g1,
                                    const float* __restrict__ g2,
                                    float* __restrict__ ws) {
  if (blockIdx.x == 0 && threadIdx.x == 0) {
    const float* gs[3] = {g0, g1, g2};
    const int ks[3]  = {5, 11, 17};
    const int off[3] = {0, 8, 32};
    for (int s = 0; s < 3; ++s) {
      const float* g = gs[s];
      int k = ks[s], h = k / 2;
      double rs = 1.0 / sqrt((double)g[h * k + h]);
      for (int j = 0; j < k; ++j)
        ws[off[s] + j] = (float)((double)g[h * k + j] * rs);
    }
  }
}

__device__ __forceinline__ float to_sgpr(float x) {
  int i = __builtin_amdgcn_readfirstlane(__builtin_bit_cast(int, x));
  return __builtin_bit_cast(float, i);
}

__device__ __forceinline__ int mod24(int x) {  // valid for 0 <= x < ~1500
  return x - 24 * ((x * 2731) >> 16);
}

// stage NROWS rows (global rows gr0..gr0+NROWS-1) into circular buffer.
// sin_ layout: [slot][plane pitch SP], b1 at +0, b2 at +SB.
// slot(row r) = (r + 8) mod 24.  Cols 144..147 of each plane are pad (never
// written, never read).
template<int NROWS>
__device__ __forceinline__ void stage_rows(const float* __restrict__ p1,
                                           const float* __restrict__ p2,
                                           float* __restrict__ sin_,
                                           int gr0, int x0, int tid) {
  constexpr int NT = NROWS * WV;
  for (int idx = tid; idx < NT; idx += 256) {
    int rr = ((idx >> 4) * 7282) >> 16;   // idx / 144  (== (idx/16)/9)
    int cc = idx - rr * WV;
    int gr = gr0 + rr;
    int gc = x0 - 8 + cc;
    float v1 = 0.f, v2 = 0.f;
    if ((unsigned)gr < (unsigned)IMG_H && (unsigned)gc < (unsigned)IMG_W) {
      int o = gr * IMG_W + gc;
      v1 = p1[o];
      v2 = p2[o];
    }
    int slot = mod24(gr + 56);            // == (gr+8) mod 24, gr >= -8
    float* p = sin_ + slot * SP + cc;
    p[0]  = v1;
    p[SB] = v2;
  }
}

// vertical pass, 2-row register blocking. task t in [0,144):
//   rp = t/36 (row PAIR in step -> rows 2rp, 2rp+1), cc = t%36 (f4 col group).
// Rows r0,r0+1 share K+1 tap rows: each tap row read ONCE (2 f4), products
// computed ONCE, accumulated into both rows' 5-plane accumulators.
// Ring addressing: two bases (pA, wrapped pB) + per-tap cndmask; all tap
// offsets are compile-time immediates (i*1184 <= 21312 < 64K).
template<int K>
__device__ __forceinline__ void v_col2(const float (&wk)[K],
                                       const float* __restrict__ sin_,
                                       float* __restrict__ sv_,
                                       int yc, int t) {
  constexpr int HK = K / 2;
  const int rp = (t * 1821) >> 16;        // t / 36, valid t < 288
  const int cc = t - rp * 36;
  const int r0 = rp * 2;
  const int cb = 4 * cc;

  float acc[5][2][4];
  #pragma unroll
  for (int d = 0; d < 5; ++d)
    #pragma unroll
    for (int r = 0; r < 2; ++r)
      #pragma unroll
      for (int j = 0; j < 4; ++j) acc[d][r][j] = 0.f;

  // slot of first tap row (row yc+r0-HK): ((yc+r0-HK)+8) mod 24
  const int us = mod24(yc + r0 + (8 - HK));
  const float* pA = sin_ + us * SP + cb;
  const float* pB = pA - NRING * SP;

  #pragma unroll
  for (int i = 0; i <= K; ++i) {
    const float* row = (us + i < NRING) ? pA : pB;
    float4 A  = *(const float4*)(row + i * SP);
    float4 Bv = *(const float4*)(row + i * SP + SB);
    float x[4] = {A.x, A.y, A.z, A.w};
    float y[4] = {Bv.x, Bv.y, Bv.z, Bv.w};
    float xx[4], yy[4], xy[4];
    #pragma unroll
    for (int j = 0; j < 4; ++j) {
      xx[j] = x[j] * x[j];
      yy[j] = y[j] * y[j];
      xy[j] = x[j] * y[j];
    }
    if (i < K) {            // contributes to row r0 with weight wk[i]
      const float w = wk[i];
      #pragma unroll
      for (int j = 0; j < 4; ++j) {
        acc[0][0][j] = fmaf(w, x[j],  acc[0][0][j]);
        acc[1][0][j] = fmaf(w, y[j],  acc[1][0][j]);
        acc[2][0][j] = fmaf(w, xx[j], acc[2][0][j]);
        acc[3][0][j] = fmaf(w, yy[j], acc[3][0][j]);
        acc[4][0][j] = fmaf(w, xy[j], acc[4][0][j]);
      }
    }
    if (i > 0) {            // contributes to row r0+1 with weight wk[i-1]
      const float w = wk[i - 1];
      #pragma unroll
      for (int j = 0; j < 4; ++j) {
        acc[0][1][j] = fmaf(w, x[j],  acc[0][1][j]);
        acc[1][1][j] = fmaf(w, y[j],  acc[1][1][j]);
        acc[2][1][j] = fmaf(w, xx[j], acc[2][1][j]);
        acc[3][1][j] = fmaf(w, yy[j], acc[3][1][j]);
        acc[4][1][j] = fmaf(w, xy[j], acc[4][1][j]);
      }
    }
  }

  #pragma unroll
  for (int d = 0; d < 5; ++d) {
    #pragma unroll
    for (int r = 0; r < 2; ++r) {
      float* vb = sv_ + d * PS + (r0 + r) * SVP + cb;
      *(float4*)vb = make_float4(acc[d][r][0], acc[d][r][1],
                                 acc[d][r][2], acc[d][r][3]);
    }
  }
}

// horizontal pass + partial ssim for (row rr, 4-col group g). Unchanged
// structure (256 balanced tasks); sv_ pitch is now SVP.
template<int K>
__device__ __forceinline__ void h_col(const float (&wk)[K],
                                      const float* __restrict__ sv_,
                                      int rr, int g, float (&accs)[4]) {
  constexpr int OFF = 8 - K / 2;
  float conv[5][4];
  #pragma unroll
  for (int d = 0; d < 5; ++d) {
    const float* vb = sv_ + d * PS + rr * SVP + 4 * g;
    float win[20];
    if constexpr (K == 5) {
      #pragma unroll
      for (int q = 1; q < 4; ++q) {
        float4 t4 = *(const float4*)(vb + 4 * q);
        win[4*q+0] = t4.x; win[4*q+1] = t4.y; win[4*q+2] = t4.z; win[4*q+3] = t4.w;
      }
    } else {
      #pragma unroll
      for (int q = 0; q < 5; ++q) {
        float4 t4 = *(const float4*)(vb + 4 * q);
        win[4*q+0] = t4.x; win[4*q+1] = t4.y; win[4*q+2] = t4.z; win[4*q+3] = t4.w;
      }
    }
    #pragma unroll
    for (int j = 0; j < 4; ++j) {
      float s = 0.f;
      #pragma unroll
      for (int t = 0; t < K; ++t) s = fmaf(wk[t], win[j + t + OFF], s);
      conv[d][j] = s;
    }
  }
  #pragma unroll
  for (int j = 0; j < 4; ++j) {
    float mu1 = conv[0][j], mu2 = conv[1][j];
    float s11 = conv[2][j], s22 = conv[3][j], s12 = conv[4][j];
    float mu11 = mu1 * mu1, mu22 = mu2 * mu2, mu12 = mu1 * mu2;
    float sg1  = fabsf(s11 - mu11);
    float sg2  = fabsf(s22 - mu22);
    float sg12 = s12 - mu12;
    float num  = fmaf(2.f, mu12, C1F) * fmaf(2.f, sg12, C2F);
    float den  = (mu11 + mu22 + C1F) * (sg1 + sg2 + C2F);
    float ssim = __fdividef(num, den);
    accs[j] += fminf(1.f, fmaxf(-1.f, ssim));
  }
}

// ---------------------------------------------------------------------------
// main fused kernel: grid = 96 images * 8 row-strips * 4 col-blocks = 3072
// block = 256 threads; LDS = 28416 (input ring) + 24320 (V planes) = 52736 B
//   -> 3 blocks/CU (12 waves/CU); 6 barriers per 8-row step
// ---------------------------------------------------------------------------
__global__ __launch_bounds__(256, 3)
void mssim_kernel(const float* __restrict__ b1, const float* __restrict__ b2,
                  const float* __restrict__ ws, float* __restrict__ out) {
  __shared__ __attribute__((aligned(16))) float sin_[NRING * SP];
  __shared__ __attribute__((aligned(16))) float sv_[5 * PS];

  const int tid = threadIdx.x;
  const int bid = blockIdx.x;
  const int img = bid >> 5;
  const int rem = bid & 31;
  const int y0  = (rem >> 2) * (RS * NSTEP);
  const int x0  = (rem & 3) * WOUT;
  const float* p1 = b1 + img * (IMG_H * IMG_W);
  const float* p2 = b2 + img * (IMG_H * IMG_W);
  float*       po = out + img * (IMG_H * IMG_W);

  // weights -> SGPRs (single scalar operand per FMA)
  float w17[17], w11[11], w5[5];
  #pragma unroll
  for (int i = 0; i < 17; ++i) w17[i] = to_sgpr(ws[32 + i]);
  #pragma unroll
  for (int i = 0; i < 11; ++i) w11[i] = to_sgpr(ws[8 + i]);
  #pragma unroll
  for (int i = 0; i < 5;  ++i) w5[i]  = to_sgpr(ws[i]);

  // preload halo rows y0-8 .. y0+7
  stage_rows<16>(p1, p2, sin_, y0 - 8, x0, tid);

  const int hr = tid >> 5;            // H row within step (0..7)
  const int hg = tid & 31;            // H 4-col group (0..31)
  const bool vact = tid < 144;        // V tasks: 4 row-pairs x 36 col groups

  #pragma unroll 1
  for (int step = 0; step < NSTEP; ++step) {
    const int yc = y0 + step * RS;
    stage_rows<RS>(p1, p2, sin_, yc + 8, x0, tid);  // rows yc+8..yc+15
    __syncthreads();

    float accs[4] = {0.f, 0.f, 0.f, 0.f};

    if (vact) v_col2<17>(w17, sin_, sv_, yc, tid);
    __syncthreads();
    h_col<17>(w17, sv_, hr, hg, accs);
    __syncthreads();

    if (vact) v_col2<11>(w11, sin_, sv_, yc, tid);
    __syncthreads();
    h_col<11>(w11, sv_, hr, hg, accs);
    __syncthreads();

    if (vact) v_col2<5>(w5, sin_, sv_, yc, tid);
    __syncthreads();
    h_col<5>(w5, sv_, hr, hg, accs);
    // no barrier needed here: next writer of sv_ (V17) is after the
    // stage+sync at the top of the next iteration; next writer of the sin_
    // slots staged there was last read by V17/V11 of THIS step.

    // out = 1 - ((sum_s (1-(clip_s+1)/2))/3 + 1)/2  ==  0.25 + sum(clip_s)/12
    float4 o = make_float4(0.25f + accs[0] * (1.f / 12.f),
                           0.25f + accs[1] * (1.f / 12.f),
                           0.25f + accs[2] * (1.f / 12.f),
                           0.25f + accs[3] * (1.f / 12.f));
    *(float4*)(po + (yc + hr) * IMG_W + x0 + 4 * hg) = o;
  }
}

extern "C" void kernel_launch(void* const* d_in, const int* in_sizes, int n_in,
                              void* d_out, int out_size, void* d_ws, size_t ws_size,
                              hipStream_t stream) {
  const float* b1 = (const float*)d_in[0];
  const float* b2 = (const float*)d_in[1];
  const float* g0 = (const float*)d_in[2];
  const float* g1 = (const float*)d_in[3];
  const float* g2 = (const float*)d_in[4];
  float* ws  = (float*)d_ws;
  float* out = (float*)d_out;

  prep_weights_kernel<<<1, 64, 0, stream>>>(g0, g1, g2, ws);
  mssim_kernel<<<3072, 256, 0, stream>>>(b1, b2, ws, out);
}